// Round 4
// baseline (2355.339 us; speedup 1.0000x reference)
//
#include <hip/hip_runtime.h>
#include <cstddef>

constexpr int NODES = 100000;
constexpr int NPB   = 64;                      // nodes per bucket
constexpr int NBUCK = (NODES + NPB - 1) / NPB; // 1563

typedef unsigned long long u64;

__device__ __forceinline__ int rfl_i(int x) {
    return __builtin_amdgcn_readfirstlane(x);
}

// ---------------- pass 1: bucket histogram ----------------

__global__ __launch_bounds__(256) void count_bucket(
    const int* __restrict__ idx, int* __restrict__ bcnt, int E)
{
    int i = blockIdx.x * blockDim.x + threadIdx.x;
    int stride = gridDim.x * blockDim.x;
    int e4 = E >> 2;
    const int4* idx4 = (const int4*)idx;
    for (int j = i; j < e4; j += stride) {
        int4 v = idx4[j];
        atomicAdd(&bcnt[v.x >> 6], 1); atomicAdd(&bcnt[v.y >> 6], 1);
        atomicAdd(&bcnt[v.z >> 6], 1); atomicAdd(&bcnt[v.w >> 6], 1);
    }
    for (int j = (e4 << 2) + i; j < E; j += stride) atomicAdd(&bcnt[idx[j] >> 6], 1);
}

// ---------------- pass 2: exclusive scan over NBUCK ----------------

__global__ __launch_bounds__(1024) void scan_buckets(
    const int* __restrict__ bcnt, int* __restrict__ bstarts, int* __restrict__ bcur)
{
    __shared__ int wsum[16];
    __shared__ int running_s;
    int tid = threadIdx.x, lane = tid & 63, wv = tid >> 6;
    if (tid == 0) running_s = 0;
    __syncthreads();
    for (int base = 0; base < NBUCK; base += 1024) {
        int i = base + tid;
        int c = (i < NBUCK) ? bcnt[i] : 0;
        int x = c;
        #pragma unroll
        for (int d = 1; d < 64; d <<= 1) {
            int v = __shfl_up(x, d);
            if (lane >= d) x += v;
        }
        if (lane == 63) wsum[wv] = x;
        __syncthreads();
        if (wv == 0 && lane < 16) {
            int y = wsum[lane];
            #pragma unroll
            for (int d = 1; d < 16; d <<= 1) {
                int v = __shfl_up(y, d);
                if (lane >= d) y += v;
            }
            wsum[lane] = y;
        }
        __syncthreads();
        int woff = (wv > 0) ? wsum[wv - 1] : 0;
        int r = running_s;
        int excl = r + woff + (x - c);
        if (i < NBUCK) { bstarts[i] = excl; bcur[i] = excl; }
        int total = wsum[15];
        __syncthreads();
        if (tid == 0) running_s = r + total;
    }
    __syncthreads();
    if (tid == 0) bstarts[NBUCK] = running_s;
}

// ---------------- pass 3: pack (edge, nloc, w) records into buckets ----------------

__device__ __forceinline__ u64 pack_rec(int e, int nloc, float w) {
    return (u64)((unsigned)e | ((unsigned)nloc << 22)) |
           ((u64)__float_as_uint(w) << 32);
}

__global__ __launch_bounds__(256) void scatter_pack(
    const int* __restrict__ idx, const float* __restrict__ wts,
    int* __restrict__ bcur, u64* __restrict__ recs, int E)
{
    int i = blockIdx.x * blockDim.x + threadIdx.x;
    int stride = gridDim.x * blockDim.x;
    int e4 = E >> 2;
    const int4*   idx4 = (const int4*)idx;
    const float4* wts4 = (const float4*)wts;
    for (int j = i; j < e4; j += stride) {
        int4   n4 = idx4[j];
        float4 w4 = wts4[j];
        int e = j << 2;
        int s0 = atomicAdd(&bcur[n4.x >> 6], 1);
        int s1 = atomicAdd(&bcur[n4.y >> 6], 1);
        int s2 = atomicAdd(&bcur[n4.z >> 6], 1);
        int s3 = atomicAdd(&bcur[n4.w >> 6], 1);
        recs[s0] = pack_rec(e + 0, n4.x & 63, w4.x);
        recs[s1] = pack_rec(e + 1, n4.y & 63, w4.y);
        recs[s2] = pack_rec(e + 2, n4.z & 63, w4.z);
        recs[s3] = pack_rec(e + 3, n4.w & 63, w4.w);
    }
    for (int e = (e4 << 2) + i; e < E; e += stride) {
        int n = idx[e];
        int s = atomicAdd(&bcur[n >> 6], 1);
        recs[s] = pack_rec(e, n & 63, wts[e]);
    }
}

// ---------------- pass 4: per-bucket gather, LDS accumulation ----------------

__global__ __launch_bounds__(256) void gather_bucket(
    const float* __restrict__ emb, const float4* __restrict__ cf4,
    const u64* __restrict__ recs, const int* __restrict__ bstarts,
    float* __restrict__ out)
{
    __shared__ float num[NPB * 64];       // 16 KB
    __shared__ float dls[NPB];            // 256 B
    __shared__ float stage[4][16 * 16];   // 4 KB (per-wave private)

    const int tid  = threadIdx.x;
    const int lane = tid & 63;
    const int wv   = tid >> 6;
    const int b    = blockIdx.x;

    // zero accumulators
    const float4 z4 = {0.f, 0.f, 0.f, 0.f};
    for (int i = tid; i < NPB * 16; i += 256) ((float4*)num)[i] = z4;
    if (tid < NPB) dls[tid] = 0.f;

    // lane = output channel; embedding row in registers
    float er[16];
    #pragma unroll
    for (int f = 0; f < 16; ++f) er[f] = emb[lane * 16 + f];
    __syncthreads();

    const int rs = rfl_i(bstarts[b]);
    const int re = rfl_i(bstarts[b + 1]);
    const int g = lane >> 2, q = lane & 3;

    float* sp = &stage[wv][0];

    // each wave takes 16-record chunks: wave wv -> chunks wv, wv+4, ...
    for (int base = rs + wv * 16; base < re; base += 64) {
        int r = base + g;
        float4 v = z4;
        float  w = 0.f;
        int    nl = 0;
        if (r < re) {
            u64 rec = recs[r];
            int e = (int)(rec & 0x3FFFFFu);
            nl = (int)((rec >> 22) & 63u);
            w  = __uint_as_float((unsigned)(rec >> 32));
            v  = cf4[(size_t)e * 4 + q];
        }
        ((float4*)sp)[lane] = v;   // stage[wv][g][q*4..q*4+3]; wave-local, lgkmcnt ordered

        #pragma unroll
        for (int j = 0; j < 16; ++j) {
            float wj  = __shfl(w,  j * 4);
            int   nlj = __shfl(nl, j * 4);
            const float* rp = sp + j * 16;
            float a = 0.f;
            #pragma unroll
            for (int f = 0; f < 16; ++f) a = fmaf(rp[f], er[f], a);
            float contrib = fmaxf(a, 0.f) * wj;
            atomicAdd(&num[nlj * 64 + lane], contrib);   // ds_add_f32, conflict-free
            if (lane == 0) atomicAdd(&dls[nlj], wj);
        }
    }
    __syncthreads();

    // epilogue: divide + coalesced store
    const int n0 = b * NPB;
    for (int i = tid; i < NPB * 16; i += 256) {
        int nl = i >> 4;
        int node = n0 + nl;
        if (node < NODES) {
            float d = dls[nl];
            float4 v = ((float4*)num)[i];
            v.x /= d; v.y /= d; v.z /= d; v.w /= d;
            ((float4*)(out + (size_t)node * 64))[i & 15] = v;
        }
    }
}

// ---------------- fallback: atomic scatter (round-1 proven) ----------------

__global__ __launch_bounds__(256) void edge_scatter_fb(
    const float* __restrict__ emb, const float* __restrict__ cf,
    const float* __restrict__ wts, const int* __restrict__ idx,
    float* __restrict__ num, float* __restrict__ den, int E)
{
    const int lane = threadIdx.x & 63;
    float er[16];
    #pragma unroll
    for (int f = 0; f < 16; ++f) er[f] = emb[lane * 16 + f];
    int wid = rfl_i((int)((blockIdx.x * blockDim.x + threadIdx.x) >> 6));
    int nw = (gridDim.x * blockDim.x) >> 6;
    for (int e = wid; e < E; e += nw) {
        const float* c = cf + (size_t)e * 16;
        float a = 0.f;
        #pragma unroll
        for (int f = 0; f < 16; ++f) a = fmaf(c[f], er[f], a);
        float wv = wts[e];
        int n = idx[e];
        unsafeAtomicAdd(num + (size_t)n * 64 + lane, fmaxf(a, 0.f) * wv);
        if (lane == 0) unsafeAtomicAdd(den + n, wv);
    }
}

__global__ __launch_bounds__(256) void divide_fb(
    float* __restrict__ out, const float* __restrict__ den, int nvec)
{
    int i = blockIdx.x * blockDim.x + threadIdx.x;
    int stride = gridDim.x * blockDim.x;
    float4* o4 = reinterpret_cast<float4*>(out);
    for (; i < nvec; i += stride) {
        float4 v = o4[i];
        float d = den[i >> 4];
        v.x /= d; v.y /= d; v.z /= d; v.w /= d;
        o4[i] = v;
    }
}

extern "C" void kernel_launch(void* const* d_in, const int* in_sizes, int n_in,
                              void* d_out, int out_size, void* d_ws, size_t ws_size,
                              hipStream_t stream)
{
    const float* emb = (const float*)d_in[0];   // (64,16)
    const float* cf  = (const float*)d_in[1];   // (E,16)
    const float* wts = (const float*)d_in[2];   // (E,)
    const int*   idx = (const int*)d_in[3];     // (E,)
    int E = in_sizes[2];
    float* out = (float*)d_out;

    // ws layout: bcnt[NBUCK] | bstarts[NBUCK+1] | bcur[NBUCK] | pad | recs[E] (8B)
    char* wsb = (char*)d_ws;
    int* bcnt    = (int*)wsb;
    int* bstarts = bcnt + NBUCK;
    int* bcur    = bstarts + NBUCK + 1;
    size_t off = (size_t)(3 * NBUCK + 1) * sizeof(int);
    off = (off + 255) & ~(size_t)255;
    u64* recs = (u64*)(wsb + off);
    size_t need = off + (size_t)E * sizeof(u64);

    if (E < (1 << 22) && ws_size >= need) {
        hipMemsetAsync(bcnt, 0, NBUCK * sizeof(int), stream);
        count_bucket<<<1024, 256, 0, stream>>>(idx, bcnt, E);
        scan_buckets<<<1, 1024, 0, stream>>>(bcnt, bstarts, bcur);
        scatter_pack<<<2048, 256, 0, stream>>>(idx, wts, bcur, recs, E);
        gather_bucket<<<NBUCK, 256, 0, stream>>>(
            emb, (const float4*)cf, recs, bstarts, out);
    } else {
        float* den = (float*)d_ws;
        hipMemsetAsync(d_out, 0, (size_t)out_size * sizeof(float), stream);
        hipMemsetAsync(d_ws, 0, (size_t)NODES * sizeof(float), stream);
        edge_scatter_fb<<<4096, 256, 0, stream>>>(emb, cf, wts, idx, out, den, E);
        divide_fb<<<2048, 256, 0, stream>>>(out, den, out_size / 4);
    }
}

// Round 5
// 1694.175 us; speedup vs baseline: 1.3903x; 1.3903x over previous
//
#include <hip/hip_runtime.h>
#include <cstddef>

constexpr int NODES = 100000;
constexpr int NPB   = 64;                      // nodes per bucket
constexpr int NBUCK = (NODES + NPB - 1) / NPB; // 1563
constexpr int NREP  = 8;                       // replicated cursors (atomic contention /8)
constexpr int NB2   = NBUCK * NREP;            // 12504

typedef unsigned long long u64;
typedef __attribute__((ext_vector_type(8)))  _Float16 f16x8;
typedef __attribute__((ext_vector_type(16))) float    f32x16;

// ---------------- pass 1: replicated bucket histogram ----------------

__global__ __launch_bounds__(256) void count_bucket(
    const int* __restrict__ idx, int* __restrict__ bcnt, int E)
{
    int* bc = bcnt + (blockIdx.x & (NREP - 1)) * NBUCK;
    int i = blockIdx.x * blockDim.x + threadIdx.x;
    int stride = gridDim.x * blockDim.x;
    int e4 = E >> 2;
    const int4* idx4 = (const int4*)idx;
    for (int j = i; j < e4; j += stride) {
        int4 v = idx4[j];
        atomicAdd(&bc[v.x >> 6], 1); atomicAdd(&bc[v.y >> 6], 1);
        atomicAdd(&bc[v.z >> 6], 1); atomicAdd(&bc[v.w >> 6], 1);
    }
    for (int j = (e4 << 2) + i; j < E; j += stride) atomicAdd(&bc[idx[j] >> 6], 1);
}

// ---------------- pass 2: exclusive scan over N entries (1 block) ----------------

__global__ __launch_bounds__(1024) void scan_any(
    const int* __restrict__ cnt, int* __restrict__ starts, int* __restrict__ cur, int N)
{
    __shared__ int wsum[16];
    __shared__ int running_s;
    int tid = threadIdx.x, lane = tid & 63, wv = tid >> 6;
    if (tid == 0) running_s = 0;
    __syncthreads();
    for (int base = 0; base < N; base += 1024) {
        int i = base + tid;
        int c = (i < N) ? cnt[i] : 0;
        int x = c;
        #pragma unroll
        for (int d = 1; d < 64; d <<= 1) {
            int v = __shfl_up(x, d);
            if (lane >= d) x += v;
        }
        if (lane == 63) wsum[wv] = x;
        __syncthreads();
        if (wv == 0 && lane < 16) {
            int y = wsum[lane];
            #pragma unroll
            for (int d = 1; d < 16; d <<= 1) {
                int v = __shfl_up(y, d);
                if (lane >= d) y += v;
            }
            wsum[lane] = y;
        }
        __syncthreads();
        int woff = (wv > 0) ? wsum[wv - 1] : 0;
        int r = running_s;
        int excl = r + woff + (x - c);
        if (i < N) { starts[i] = excl; cur[i] = excl; }
        int total = wsum[15];
        __syncthreads();
        if (tid == 0) running_s = r + total;
    }
    __syncthreads();
    if (tid == 0) starts[N] = running_s;
}

// ---------------- pass 3: pack (edge, nloc, w) into replicated bucket regions ----------------

__device__ __forceinline__ u64 pack_rec(int e, int nloc, float w) {
    return (u64)((unsigned)e | ((unsigned)nloc << 22)) |
           ((u64)__float_as_uint(w) << 32);
}

__global__ __launch_bounds__(256) void scatter_pack(
    const int* __restrict__ idx, const float* __restrict__ wts,
    int* __restrict__ bcur, u64* __restrict__ recs,
    float* __restrict__ den, int E)
{
    int* cur = bcur + (blockIdx.x & (NREP - 1)) * NBUCK;
    int i = blockIdx.x * blockDim.x + threadIdx.x;
    int stride = gridDim.x * blockDim.x;
    int e4 = E >> 2;
    const int4*   idx4 = (const int4*)idx;
    const float4* wts4 = (const float4*)wts;
    for (int j = i; j < e4; j += stride) {
        int4   n4 = idx4[j];
        float4 w4 = wts4[j];
        int e = j << 2;
        int s0 = atomicAdd(&cur[n4.x >> 6], 1);
        int s1 = atomicAdd(&cur[n4.y >> 6], 1);
        int s2 = atomicAdd(&cur[n4.z >> 6], 1);
        int s3 = atomicAdd(&cur[n4.w >> 6], 1);
        recs[s0] = pack_rec(e + 0, n4.x & 63, w4.x);
        recs[s1] = pack_rec(e + 1, n4.y & 63, w4.y);
        recs[s2] = pack_rec(e + 2, n4.z & 63, w4.z);
        recs[s3] = pack_rec(e + 3, n4.w & 63, w4.w);
        unsafeAtomicAdd(&den[n4.x], w4.x);
        unsafeAtomicAdd(&den[n4.y], w4.y);
        unsafeAtomicAdd(&den[n4.z], w4.z);
        unsafeAtomicAdd(&den[n4.w], w4.w);
    }
    for (int e = (e4 << 2) + i; e < E; e += stride) {
        int n = idx[e];
        float w = wts[e];
        int s = atomicAdd(&cur[n >> 6], 1);
        recs[s] = pack_rec(e, n & 63, w);
        unsafeAtomicAdd(&den[n], w);
    }
}

// ---------------- pass 4: per-bucket MFMA gather ----------------
// feats[32 edges][32 u] = (w*cf)[32e][16f] x emb^T[16f][32u], relu, ds_add into num.
// D layout (verified, m74/m101): col = lane&31, row = (reg&3) + 8*(reg>>2) + 4*(lane>>5).

__global__ __launch_bounds__(256) void gather_mfma(
    const float* __restrict__ emb, const float4* __restrict__ cf4,
    const u64* __restrict__ recs, const int* __restrict__ bstarts,
    const float* __restrict__ den, float* __restrict__ out)
{
    __shared__ float num[NPB * 64];   // 16 KB
    __shared__ int   nlbuf[4][32];
    __shared__ float dls[NPB];

    const int tid = threadIdx.x;
    const int l   = tid & 63;
    const int wv  = tid >> 6;
    const int b   = blockIdx.x;
    const int ucol = l & 31;
    const int h    = l >> 5;

    const float4 z4 = {0.f, 0.f, 0.f, 0.f};
    for (int i = tid; i < NPB * 16; i += 256) ((float4*)num)[i] = z4;

    // B fragments: emb^T, lane supplies B[k=8h+j][n=ucol] = emb[ucol][8h+j]
    f16x8 b0, b1;
    #pragma unroll
    for (int j = 0; j < 8; ++j) {
        b0[j] = (_Float16)emb[ucol * 16 + 8 * h + j];
        b1[j] = (_Float16)emb[(ucol + 32) * 16 + 8 * h + j];
    }
    __syncthreads();

    for (int rep = 0; rep < NREP; ++rep) {
        const int rs = bstarts[rep * NBUCK + b];
        const int re = bstarts[rep * NBUCK + b + 1];
        for (int base = rs + wv * 32; base < re; base += 128) {
            int r = base + ucol;
            u64 rec = 0;
            if (r < re) rec = recs[r];
            int   e  = (int)(rec & 0x3FFFFFu);
            int   nl = (int)((rec >> 22) & 63u);
            float w  = __uint_as_float((unsigned)(rec >> 32));
            if (l < 32) nlbuf[wv][l] = nl;
            // A fragment: lane supplies A[row=ucol][k=8h+j] = w*cf[edge ucol][8h+j]
            float4 c0 = cf4[(size_t)e * 4 + h * 2];
            float4 c1 = cf4[(size_t)e * 4 + h * 2 + 1];
            f16x8 a;
            a[0] = (_Float16)(c0.x * w); a[1] = (_Float16)(c0.y * w);
            a[2] = (_Float16)(c0.z * w); a[3] = (_Float16)(c0.w * w);
            a[4] = (_Float16)(c1.x * w); a[5] = (_Float16)(c1.y * w);
            a[6] = (_Float16)(c1.z * w); a[7] = (_Float16)(c1.w * w);
            f32x16 z;
            #pragma unroll
            for (int i = 0; i < 16; ++i) z[i] = 0.f;
            f32x16 d0 = __builtin_amdgcn_mfma_f32_32x32x16_f16(a, b0, z, 0, 0, 0);
            f32x16 d1 = __builtin_amdgcn_mfma_f32_32x32x16_f16(a, b1, z, 0, 0, 0);
            #pragma unroll
            for (int j = 0; j < 4; ++j) {
                int4 nj = *(const int4*)&nlbuf[wv][8 * j + 4 * h];
                int r0 = 4 * j;
                atomicAdd(&num[nj.x * 64 + ucol],      fmaxf(d0[r0 + 0], 0.f));
                atomicAdd(&num[nj.x * 64 + 32 + ucol], fmaxf(d1[r0 + 0], 0.f));
                atomicAdd(&num[nj.y * 64 + ucol],      fmaxf(d0[r0 + 1], 0.f));
                atomicAdd(&num[nj.y * 64 + 32 + ucol], fmaxf(d1[r0 + 1], 0.f));
                atomicAdd(&num[nj.z * 64 + ucol],      fmaxf(d0[r0 + 2], 0.f));
                atomicAdd(&num[nj.z * 64 + 32 + ucol], fmaxf(d1[r0 + 2], 0.f));
                atomicAdd(&num[nj.w * 64 + ucol],      fmaxf(d0[r0 + 3], 0.f));
                atomicAdd(&num[nj.w * 64 + 32 + ucol], fmaxf(d1[r0 + 3], 0.f));
            }
        }
    }
    __syncthreads();

    if (tid < NPB) {
        int node = b * NPB + tid;
        dls[tid] = (node < NODES) ? den[node] : 1.f;
    }
    __syncthreads();

    const int n0 = b * NPB;
    for (int i = tid; i < NPB * 16; i += 256) {
        int nl = i >> 4;
        int node = n0 + nl;
        if (node < NODES) {
            float d = dls[nl];
            float4 v = ((float4*)num)[i];
            v.x /= d; v.y /= d; v.z /= d; v.w /= d;
            ((float4*)(out + (size_t)node * 64))[i & 15] = v;
        }
    }
}

// ---------------- fallback: atomic scatter (round-1 proven) ----------------

__global__ __launch_bounds__(256) void edge_scatter_fb(
    const float* __restrict__ emb, const float* __restrict__ cf,
    const float* __restrict__ wts, const int* __restrict__ idx,
    float* __restrict__ num, float* __restrict__ den, int E)
{
    const int lane = threadIdx.x & 63;
    float er[16];
    #pragma unroll
    for (int f = 0; f < 16; ++f) er[f] = emb[lane * 16 + f];
    int wid = __builtin_amdgcn_readfirstlane(
        (int)((blockIdx.x * blockDim.x + threadIdx.x) >> 6));
    int nw = (gridDim.x * blockDim.x) >> 6;
    for (int e = wid; e < E; e += nw) {
        const float* c = cf + (size_t)e * 16;
        float a = 0.f;
        #pragma unroll
        for (int f = 0; f < 16; ++f) a = fmaf(c[f], er[f], a);
        float wv = wts[e];
        int n = idx[e];
        unsafeAtomicAdd(num + (size_t)n * 64 + lane, fmaxf(a, 0.f) * wv);
        if (lane == 0) unsafeAtomicAdd(den + n, wv);
    }
}

__global__ __launch_bounds__(256) void divide_fb(
    float* __restrict__ out, const float* __restrict__ den, int nvec)
{
    int i = blockIdx.x * blockDim.x + threadIdx.x;
    int stride = gridDim.x * blockDim.x;
    float4* o4 = reinterpret_cast<float4*>(out);
    for (; i < nvec; i += stride) {
        float4 v = o4[i];
        float d = den[i >> 4];
        v.x /= d; v.y /= d; v.z /= d; v.w /= d;
        o4[i] = v;
    }
}

extern "C" void kernel_launch(void* const* d_in, const int* in_sizes, int n_in,
                              void* d_out, int out_size, void* d_ws, size_t ws_size,
                              hipStream_t stream)
{
    const float* emb = (const float*)d_in[0];   // (64,16)
    const float* cf  = (const float*)d_in[1];   // (E,16)
    const float* wts = (const float*)d_in[2];   // (E,)
    const int*   idx = (const int*)d_in[3];     // (E,)
    int E = in_sizes[2];
    float* out = (float*)d_out;

    // ws layout: bcnt[NB2] | bstarts[NB2+1] | bcur[NB2] | den[NODES] | pad | recs[E]
    char* wsb = (char*)d_ws;
    int* bcnt    = (int*)wsb;
    int* bstarts = bcnt + NB2;
    int* bcur    = bstarts + NB2 + 1;
    float* den   = (float*)(bcur + NB2);
    size_t off = (size_t)(3 * NB2 + 1 + NODES) * sizeof(int);
    off = (off + 255) & ~(size_t)255;
    u64* recs = (u64*)(wsb + off);
    size_t need = off + (size_t)E * sizeof(u64);

    if (E < (1 << 22) && ws_size >= need) {
        hipMemsetAsync(bcnt, 0, NB2 * sizeof(int), stream);
        hipMemsetAsync(den, 0, NODES * sizeof(float), stream);
        count_bucket<<<2048, 256, 0, stream>>>(idx, bcnt, E);
        scan_any<<<1, 1024, 0, stream>>>(bcnt, bstarts, bcur, NB2);
        scatter_pack<<<2048, 256, 0, stream>>>(idx, wts, bcur, recs, den, E);
        gather_mfma<<<NBUCK, 256, 0, stream>>>(
            emb, (const float4*)cf, recs, bstarts, den, out);
    } else {
        float* den2 = (float*)d_ws;
        hipMemsetAsync(d_out, 0, (size_t)out_size * sizeof(float), stream);
        hipMemsetAsync(d_ws, 0, (size_t)NODES * sizeof(float), stream);
        edge_scatter_fb<<<4096, 256, 0, stream>>>(emb, cf, wts, idx, out, den2, E);
        divide_fb<<<2048, 256, 0, stream>>>(out, den2, out_size / 4);
    }
}